// Round 12
// baseline (2649.947 us; speedup 1.0000x reference)
//
#include <hip/hip_runtime.h>
#include <hip/hip_cooperative_groups.h>

namespace cg = cooperative_groups;

#define THREADS 256
#define TILE 8192
#define TPB_S 512
#define EPT 16              // TILE / TPB_S
#define BUCKET_BITS 10
#define BUCKET_SIZE 1024
#define NT_MAX 2048         // max tiles supported by merge (E <= 16.7M)
#define STAGE_CAP 15616     // 61KB stage; merge LDS total 75KB -> 2 blocks/CU
#define CAP2 16640          // reorder stage (65KB); bucket len > CAP2 -> degenerate (no reorder)
#define NSLICE 8
#define SLICE_SHIFT 17      // 128K nodes = 2MB float4 window per slice
#define MSK 0xFFFFFu

__device__ __forceinline__ long long llmin(long long a, long long b) { return a < b ? a : b; }

// ---------------- common ----------------

__global__ void detect_i64_kernel(const int* __restrict__ e, int* __restrict__ flag) {
    if (blockIdx.x == 0 && threadIdx.x == 0) {
        bool all_odd_zero = true, any_even = false;
#pragma unroll
        for (int k = 0; k < 16; ++k) {
            if (e[2 * k + 1] != 0) all_odd_zero = false;
            if (e[2 * k] != 0) any_even = true;
        }
        *flag = (all_odd_zero && any_even) ? 1 : 0;
    }
}

// ---------------- single-pass tile-local counting sort (champion R6) ----------------

__global__ __launch_bounds__(TPB_S) void binsort_kernel(
        const int* __restrict__ e, long long E, const int* __restrict__ flag,
        int nbuck, int* __restrict__ packed, int* __restrict__ ofs) {
    __shared__ int hist[1024];
    __shared__ int sarr[TPB_S];
    __shared__ int srec[TILE];
    const int tid = threadIdx.x;
    hist[tid] = 0;
    hist[tid + TPB_S] = 0;
    __syncthreads();

    const bool i64 = (*flag != 0);
    const long long beg = (long long)blockIdx.x * TILE;
    const int tile_len = (int)llmin((long long)TILE, E - beg);

    int rec[EPT];
    int bkt[EPT];
#pragma unroll
    for (int k = 0; k < EPT; ++k) {
        int j = tid + k * TPB_S;
        bkt[k] = -1;
        if (j < tile_len) {
            long long idx = beg + j;
            int s, d;
            if (i64) { s = ((const int2*)e)[idx].x; d = ((const int2*)e)[E + idx].x; }
            else     { s = e[idx];                  d = e[E + idx]; }
            bkt[k] = d >> BUCKET_BITS;
            rec[k] = ((d & (BUCKET_SIZE - 1)) << 20) | s;
            atomicAdd(&hist[bkt[k]], 1);
        }
    }
    __syncthreads();

    int v0 = hist[2 * tid], v1 = hist[2 * tid + 1];
    sarr[tid] = v0 + v1;
    __syncthreads();
    for (int off = 1; off < TPB_S; off <<= 1) {
        int t = (tid >= off) ? sarr[tid - off] : 0;
        __syncthreads();
        sarr[tid] += t;
        __syncthreads();
    }
    int excl = (tid == 0) ? 0 : sarr[tid - 1];
    hist[2 * tid] = excl;
    hist[2 * tid + 1] = excl + v0;
    __syncthreads();

    int* orow = ofs + (size_t)blockIdx.x * nbuck;
    if (tid < nbuck) orow[tid] = hist[tid];
    if (tid + TPB_S < nbuck) orow[tid + TPB_S] = hist[tid + TPB_S];
    __syncthreads();

#pragma unroll
    for (int k = 0; k < EPT; ++k) {
        if (bkt[k] >= 0) {
            int pos = atomicAdd(&hist[bkt[k]], 1);
            srec[pos] = rec[k];
        }
    }
    __syncthreads();

    int* prow = packed + (size_t)blockIdx.x * TILE;
    for (int j = tid; j < tile_len; j += TPB_S) prow[j] = srec[j];
}

// transpose ofs[t][b] -> ofsT[b][t]
#define TRT 32
__global__ void transpose_kernel(const int* __restrict__ in, int rows, int cols,
                                 int* __restrict__ outT) {
    __shared__ int tb[TRT][TRT + 1];
    int c0 = blockIdx.x * TRT, r0 = blockIdx.y * TRT;
    int lx = threadIdx.x, ly = threadIdx.y;   // 32 x 8
    for (int dy = ly; dy < TRT; dy += 8) {
        int r = r0 + dy, c = c0 + lx;
        if (r < rows && c < cols) tb[dy][lx] = in[(size_t)r * cols + c];
    }
    __syncthreads();
    for (int dy = ly; dy < TRT; dy += 8) {
        int r = c0 + dy, c = r0 + lx;
        if (r < cols && c < rows) outT[(size_t)r * rows + c] = tb[lx][dy];
    }
}

// ---------------- bucket sizes + global offsets (no atomics) ----------------

__global__ __launch_bounds__(THREADS) void bcnt_kernel(
        const int* __restrict__ ofsT, long long E, int ntiles, int nbuck,
        int* __restrict__ bcnt) {
    __shared__ int sh[THREADS];
    const int b = blockIdx.x, tid = threadIdx.x;
    const int* row0 = ofsT + (size_t)b * ntiles;
    const int* row1 = row0 + ntiles;
    const bool last_b = (b == nbuck - 1);
    int s = 0;
    for (int t = tid; t < ntiles; t += THREADS) {
        int o = row0[t];
        int tl = (t == ntiles - 1) ? (int)(E - (long long)t * TILE) : TILE;
        int o2 = last_b ? tl : row1[t];
        s += o2 - o;
    }
    sh[tid] = s;
    __syncthreads();
    for (int off = THREADS >> 1; off > 0; off >>= 1) {
        if (tid < off) sh[tid] += sh[tid + off];
        __syncthreads();
    }
    if (tid == 0) bcnt[b] = sh[0];
}

__global__ __launch_bounds__(1024) void bscan_kernel(
        const int* __restrict__ bcnt, int nbuck, int* __restrict__ bs) {
    __shared__ int sh[1024];
    int tid = threadIdx.x;
    int v = (tid < nbuck) ? bcnt[tid] : 0;
    sh[tid] = v;
    __syncthreads();
    for (int off = 1; off < 1024; off <<= 1) {
        int t = (tid >= off) ? sh[tid - off] : 0;
        __syncthreads();
        sh[tid] += t;
        __syncthreads();
    }
    if (tid < nbuck) bs[tid] = sh[tid] - v;
    if (tid == nbuck - 1) bs[nbuck] = sh[tid];
}

// ---------------- merge: tile-runs -> bucket-contiguous + fused deg/dinv/p ----------------

__global__ __launch_bounds__(TPB_S) void merge_kernel(
        const int* __restrict__ ofsT, const int* __restrict__ packed,
        const int* __restrict__ bs, long long E, int ntiles, int nbuck,
        const float* __restrict__ x,
        int* __restrict__ merged, float* __restrict__ dinv, float* __restrict__ p,
        int N) {
    __shared__ int lofs[NT_MAX];
    __shared__ int tsum[TPB_S];
    __shared__ int stage[STAGE_CAP];
    __shared__ int cnt[BUCKET_SIZE];
    const int tid = threadIdx.x, b = blockIdx.x;
    const int* row0 = ofsT + (size_t)b * ntiles;
    const int* row1 = row0 + ntiles;
    const bool last_b = (b == nbuck - 1);
    const int per = (ntiles + TPB_S - 1) / TPB_S;
    const int t0 = tid * per;

    for (int k = tid; k < BUCKET_SIZE; k += TPB_S) cnt[k] = 0;

    int s = 0;
    for (int k = 0; k < per; ++k) {
        int t = t0 + k;
        if (t < ntiles) {
            int o = row0[t];
            int tl = (t == ntiles - 1) ? (int)(E - (long long)t * TILE) : TILE;
            int o2 = last_b ? tl : row1[t];
            lofs[t] = s;
            s += o2 - o;
        }
    }
    tsum[tid] = s;
    __syncthreads();
    for (int off = 1; off < TPB_S; off <<= 1) {
        int t = (tid >= off) ? tsum[tid - off] : 0;
        __syncthreads();
        tsum[tid] += t;
        __syncthreads();
    }
    const int excl = tsum[tid] - s;
    const int total = tsum[TPB_S - 1];
    for (int k = 0; k < per; ++k) {
        int t = t0 + k;
        if (t < ntiles) lofs[t] += excl;
    }
    __syncthreads();

    const int bsb = bs[b];
    for (int k = 0; k < per; ++k) {
        int t = t0 + k;
        if (t >= ntiles) break;
        int o = row0[t];
        int tl = (t == ntiles - 1) ? (int)(E - (long long)t * TILE) : TILE;
        int o2 = last_b ? tl : row1[t];
        const int* pr = packed + (size_t)t * TILE;
        int q = lofs[t];
        int j = o;
        for (; j + 4 <= o2; j += 4, q += 4) {
            int a0 = pr[j], a1 = pr[j + 1], a2 = pr[j + 2], a3 = pr[j + 3];
            atomicAdd(&cnt[((unsigned)a0) >> 20], 1);
            atomicAdd(&cnt[((unsigned)a1) >> 20], 1);
            atomicAdd(&cnt[((unsigned)a2) >> 20], 1);
            atomicAdd(&cnt[((unsigned)a3) >> 20], 1);
            if (q + 3 < STAGE_CAP) {
                stage[q] = a0; stage[q + 1] = a1; stage[q + 2] = a2; stage[q + 3] = a3;
            } else {
                if (q < STAGE_CAP) stage[q] = a0; else merged[bsb + q] = a0;
                if (q + 1 < STAGE_CAP) stage[q + 1] = a1; else merged[bsb + q + 1] = a1;
                if (q + 2 < STAGE_CAP) stage[q + 2] = a2; else merged[bsb + q + 2] = a2;
                merged[bsb + q + 3] = a3;
            }
        }
        for (; j < o2; ++j, ++q) {
            int a0 = pr[j];
            atomicAdd(&cnt[((unsigned)a0) >> 20], 1);
            if (q < STAGE_CAP) stage[q] = a0; else merged[bsb + q] = a0;
        }
    }
    __syncthreads();

    const int wlen = total < STAGE_CAP ? total : STAGE_CAP;
    for (int j = tid; j < wlen; j += TPB_S) merged[bsb + j] = stage[j];

    int nbase = b << BUCKET_BITS;
    for (int j = tid; j < BUCKET_SIZE; j += TPB_S) {
        int i = nbase + j;
        if (i < N) {
            float di = rsqrtf((float)cnt[j] + 1.0f);
            dinv[i] = di;
            p[i] = x[i] * di;
        }
    }
}

// ---------------- slice_reorder: in-place permute each bucket segment by src-slice ----
// LDS: stage2 65KB + f 8KB + sarr 1KB = 74KB -> 2 blocks/CU. Reads its contiguous
// segment twice (count pass + place pass, second L2-warm), writes once coalesced.

__global__ __launch_bounds__(THREADS) void slice_reorder_kernel(
        const int* __restrict__ bs, int* __restrict__ merged, int* __restrict__ sofs) {
    __shared__ int stage2[CAP2];
    __shared__ int f[NSLICE * THREADS];
    __shared__ int sarr[THREADS];
    const int b = blockIdx.x, tid = threadIdx.x;
    const int base = bs[b];
    const int len = bs[b + 1] - base;

    if (len > CAP2) {   // ~8-sigma rare: skip reorder; slice 0 = whole segment
        if (tid == 0) {
            sofs[b * 9] = 0;
            for (int s2 = 1; s2 <= NSLICE; ++s2) sofs[b * 9 + s2] = len;
        }
        return;
    }

    int c[NSLICE];
#pragma unroll
    for (int i = 0; i < NSLICE; ++i) c[i] = 0;
    for (int j = tid; j < len; j += THREADS) {
        unsigned r = (unsigned)merged[base + j];
        c[(r & MSK) >> SLICE_SHIFT]++;
    }
#pragma unroll
    for (int sl = 0; sl < NSLICE; ++sl) f[sl * THREADS + tid] = c[sl];
    __syncthreads();

    // exclusive scan over flat [slice][tid] grid (slice-major)
    int loc[NSLICE];
    int s = 0;
#pragma unroll
    for (int j = 0; j < NSLICE; ++j) { loc[j] = f[tid * NSLICE + j]; s += loc[j]; }
    sarr[tid] = s;
    __syncthreads();
    for (int off = 1; off < THREADS; off <<= 1) {
        int t = (tid >= off) ? sarr[tid - off] : 0;
        __syncthreads();
        sarr[tid] += t;
        __syncthreads();
    }
    int ex = sarr[tid] - s;
#pragma unroll
    for (int j = 0; j < NSLICE; ++j) { f[tid * NSLICE + j] = ex; ex += loc[j]; }
    __syncthreads();

    int cur[NSLICE];
#pragma unroll
    for (int sl = 0; sl < NSLICE; ++sl) cur[sl] = f[sl * THREADS + tid];
    // slice boundary = cursor of thread 0 of each slice
    if (tid < NSLICE) sofs[b * 9 + tid] = f[tid * THREADS];
    if (tid == 0) sofs[b * 9 + NSLICE] = len;

    for (int j = tid; j < len; j += THREADS) {
        int r = merged[base + j];
        int sl = (((unsigned)r) & MSK) >> SLICE_SHIFT;
        stage2[cur[sl]++] = r;
    }
    __syncthreads();
    for (int j = tid; j < len; j += THREADS) merged[base + j] = stage2[j];
}

// ---------------- layer1: scalar gather (4MB table, L2-friendly) ----------------

__global__ void layer1_bucket_kernel(const int* __restrict__ bs, const int* __restrict__ merged,
                                     const float* __restrict__ p, const float* __restrict__ dinv,
                                     const float* __restrict__ W1, const float* __restrict__ b1,
                                     const float* __restrict__ W2,
                                     float4* __restrict__ y2, int N) {
    __shared__ float acc[BUCKET_SIZE];
    for (int k = threadIdx.x; k < BUCKET_SIZE; k += blockDim.x) acc[k] = 0.0f;
    __syncthreads();
    int beg = bs[blockIdx.x], end = bs[blockIdx.x + 1];
    int stride = blockDim.x;
    int k = beg + threadIdx.x;
    for (; k + 3 * stride < end; k += 4 * stride) {
        unsigned r0 = merged[k], r1 = merged[k + stride];
        unsigned r2 = merged[k + 2 * stride], r3 = merged[k + 3 * stride];
        float v0 = p[r0 & MSK], v1 = p[r1 & MSK];
        float v2 = p[r2 & MSK], v3 = p[r3 & MSK];
        atomicAdd(&acc[r0 >> 20], v0);
        atomicAdd(&acc[r1 >> 20], v1);
        atomicAdd(&acc[r2 >> 20], v2);
        atomicAdd(&acc[r3 >> 20], v3);
    }
    for (; k < end; k += stride) {
        unsigned rec = (unsigned)merged[k];
        atomicAdd(&acc[rec >> 20], p[rec & MSK]);
    }
    __syncthreads();
    int base = blockIdx.x << BUCKET_BITS;
    for (int j = threadIdx.x; j < BUCKET_SIZE; j += blockDim.x) {
        int i = base + j;
        if (i >= N) continue;
        float di = dinv[i];
        float t = di * (acc[j] + p[i]);
        float h0 = fmaxf(t * W1[0] + b1[0], 0.0f);
        float h1 = fmaxf(t * W1[1] + b1[1], 0.0f);
        float h2 = fmaxf(t * W1[2] + b1[2], 0.0f);
        float4 o;
        o.x = di * (h0 * W2[0] + h1 * W2[3] + h2 * W2[6]);
        o.y = di * (h0 * W2[1] + h1 * W2[4] + h2 * W2[7]);
        o.z = di * (h0 * W2[2] + h1 * W2[5] + h2 * W2[8]);
        o.w = 0.0f;
        y2[i] = o;
    }
}

// ---------------- mid/last: cooperative slice-phased gather ----------------
// All blocks process slice s simultaneously (grid.sync between slices) -> the
// 2MB y-window is L2-resident per XCD -> table lines fetched once per XCD per
// slice (~128MB total) instead of once per bucket (~730MB).

__device__ __forceinline__ void gather_slice(const int* merged, const float4* y,
                                             float* acc, int beg, int end, int stride) {
    int k = beg + threadIdx.x;
    for (; k + 3 * stride < end; k += 4 * stride) {
        unsigned r0 = merged[k], r1 = merged[k + stride];
        unsigned r2 = merged[k + 2 * stride], r3 = merged[k + 3 * stride];
        float4 v0 = y[r0 & MSK], v1 = y[r1 & MSK];
        float4 v2 = y[r2 & MSK], v3 = y[r3 & MSK];
        int d0 = (r0 >> 20) * 3, d1 = (r1 >> 20) * 3, d2 = (r2 >> 20) * 3, d3 = (r3 >> 20) * 3;
        atomicAdd(&acc[d0 + 0], v0.x); atomicAdd(&acc[d0 + 1], v0.y); atomicAdd(&acc[d0 + 2], v0.z);
        atomicAdd(&acc[d1 + 0], v1.x); atomicAdd(&acc[d1 + 1], v1.y); atomicAdd(&acc[d1 + 2], v1.z);
        atomicAdd(&acc[d2 + 0], v2.x); atomicAdd(&acc[d2 + 1], v2.y); atomicAdd(&acc[d2 + 2], v2.z);
        atomicAdd(&acc[d3 + 0], v3.x); atomicAdd(&acc[d3 + 1], v3.y); atomicAdd(&acc[d3 + 2], v3.z);
    }
    for (; k < end; k += stride) {
        unsigned rec = (unsigned)merged[k];
        float4 v = y[rec & MSK];
        int dl = (rec >> 20) * 3;
        atomicAdd(&acc[dl + 0], v.x);
        atomicAdd(&acc[dl + 1], v.y);
        atomicAdd(&acc[dl + 2], v.z);
    }
}

__global__ __launch_bounds__(THREADS) void layer_mid_coop_kernel(
        const int* __restrict__ bs, const int* __restrict__ sofs,
        const int* __restrict__ merged,
        const float4* __restrict__ y, const float* __restrict__ dinv,
        const float* __restrict__ b, const float* __restrict__ Wn,
        float4* __restrict__ ynext, int N) {
    __shared__ float acc[BUCKET_SIZE * 3];
    for (int k = threadIdx.x; k < BUCKET_SIZE * 3; k += blockDim.x) acc[k] = 0.0f;
    __syncthreads();
    cg::grid_group g = cg::this_grid();
    const int bb = blockIdx.x;
    const int base = bs[bb];
    for (int s = 0; s < NSLICE; ++s) {
        int beg = base + sofs[bb * 9 + s];
        int end = base + sofs[bb * 9 + s + 1];
        gather_slice(merged, y, acc, beg, end, blockDim.x);
        g.sync();
    }
    __syncthreads();
    int nbase = bb << BUCKET_BITS;
    for (int j = threadIdx.x; j < BUCKET_SIZE; j += blockDim.x) {
        int i = nbase + j;
        if (i >= N) continue;
        float di = dinv[i];
        float4 yi = y[i];
        float h0 = fmaxf(di * (acc[j * 3 + 0] + yi.x) + b[0], 0.0f);
        float h1 = fmaxf(di * (acc[j * 3 + 1] + yi.y) + b[1], 0.0f);
        float h2 = fmaxf(di * (acc[j * 3 + 2] + yi.z) + b[2], 0.0f);
        float4 o;
        o.x = di * (h0 * Wn[0] + h1 * Wn[3] + h2 * Wn[6]);
        o.y = di * (h0 * Wn[1] + h1 * Wn[4] + h2 * Wn[7]);
        o.z = di * (h0 * Wn[2] + h1 * Wn[5] + h2 * Wn[8]);
        o.w = 0.0f;
        ynext[i] = o;
    }
}

__global__ __launch_bounds__(THREADS) void layer_last_coop_kernel(
        const int* __restrict__ bs, const int* __restrict__ sofs,
        const int* __restrict__ merged,
        const float4* __restrict__ y, const float* __restrict__ dinv,
        const float* __restrict__ b,
        float* __restrict__ out, int N) {
    __shared__ float acc[BUCKET_SIZE * 3];
    for (int k = threadIdx.x; k < BUCKET_SIZE * 3; k += blockDim.x) acc[k] = 0.0f;
    __syncthreads();
    cg::grid_group g = cg::this_grid();
    const int bb = blockIdx.x;
    const int base = bs[bb];
    for (int s = 0; s < NSLICE; ++s) {
        int beg = base + sofs[bb * 9 + s];
        int end = base + sofs[bb * 9 + s + 1];
        gather_slice(merged, y, acc, beg, end, blockDim.x);
        g.sync();
    }
    __syncthreads();
    int nbase = bb << BUCKET_BITS;
    for (int j = threadIdx.x; j < BUCKET_SIZE; j += blockDim.x) {
        int i = nbase + j;
        if (i >= N) continue;
        float di = dinv[i];
        float4 yi = y[i];
        out[i * 3 + 0] = fmaxf(di * (acc[j * 3 + 0] + yi.x) + b[0], 0.0f);
        out[i * 3 + 1] = fmaxf(di * (acc[j * 3 + 1] + yi.y) + b[1], 0.0f);
        out[i * 3 + 2] = fmaxf(di * (acc[j * 3 + 2] + yi.z) + b[2], 0.0f);
    }
}

// ---------------- non-coop fallback mid/last (champion R6/R10) ----------------

__global__ void layer_mid_bucket_kernel(const int* __restrict__ bs, const int* __restrict__ merged,
                                        const float4* __restrict__ y, const float* __restrict__ dinv,
                                        const float* __restrict__ b, const float* __restrict__ Wn,
                                        float4* __restrict__ ynext, int N) {
    __shared__ float acc[BUCKET_SIZE * 3];
    for (int k = threadIdx.x; k < BUCKET_SIZE * 3; k += blockDim.x) acc[k] = 0.0f;
    __syncthreads();
    int beg = bs[blockIdx.x], end = bs[blockIdx.x + 1];
    gather_slice(merged, y, acc, beg, end, blockDim.x);
    __syncthreads();
    int base = blockIdx.x << BUCKET_BITS;
    for (int j = threadIdx.x; j < BUCKET_SIZE; j += blockDim.x) {
        int i = base + j;
        if (i >= N) continue;
        float di = dinv[i];
        float4 yi = y[i];
        float h0 = fmaxf(di * (acc[j * 3 + 0] + yi.x) + b[0], 0.0f);
        float h1 = fmaxf(di * (acc[j * 3 + 1] + yi.y) + b[1], 0.0f);
        float h2 = fmaxf(di * (acc[j * 3 + 2] + yi.z) + b[2], 0.0f);
        float4 o;
        o.x = di * (h0 * Wn[0] + h1 * Wn[3] + h2 * Wn[6]);
        o.y = di * (h0 * Wn[1] + h1 * Wn[4] + h2 * Wn[7]);
        o.z = di * (h0 * Wn[2] + h1 * Wn[5] + h2 * Wn[8]);
        o.w = 0.0f;
        ynext[i] = o;
    }
}

__global__ void layer_last_bucket_kernel(const int* __restrict__ bs, const int* __restrict__ merged,
                                         const float4* __restrict__ y, const float* __restrict__ dinv,
                                         const float* __restrict__ b,
                                         float* __restrict__ out, int N) {
    __shared__ float acc[BUCKET_SIZE * 3];
    for (int k = threadIdx.x; k < BUCKET_SIZE * 3; k += blockDim.x) acc[k] = 0.0f;
    __syncthreads();
    int beg = bs[blockIdx.x], end = bs[blockIdx.x + 1];
    gather_slice(merged, y, acc, beg, end, blockDim.x);
    __syncthreads();
    int base = blockIdx.x << BUCKET_BITS;
    for (int j = threadIdx.x; j < BUCKET_SIZE; j += blockDim.x) {
        int i = base + j;
        if (i >= N) continue;
        float di = dinv[i];
        float4 yi = y[i];
        out[i * 3 + 0] = fmaxf(di * (acc[j * 3 + 0] + yi.x) + b[0], 0.0f);
        out[i * 3 + 1] = fmaxf(di * (acc[j * 3 + 1] + yi.y) + b[1], 0.0f);
        out[i * 3 + 2] = fmaxf(di * (acc[j * 3 + 2] + yi.z) + b[2], 0.0f);
    }
}

// ---------------- fallback (atomic scatter path, known-good R0) ----------------

__global__ void deg_kernel(const int* __restrict__ e, long long E,
                           const int* __restrict__ flag, float* __restrict__ deg) {
    const bool i64 = (*flag != 0);
    long long i = (long long)blockIdx.x * blockDim.x + threadIdx.x;
    const long long stride = (long long)gridDim.x * blockDim.x;
    for (; i < E; i += stride) {
        long long t = i64 ? (long long)e[2 * E + 2 * i] : (long long)e[E + i];
        atomicAdd(deg + t, 1.0f);
    }
}

__global__ void node_init_kernel(const float* __restrict__ x, const float* __restrict__ W1,
                                 float* __restrict__ deg_dinv, float* __restrict__ A, int N) {
    int i = blockIdx.x * blockDim.x + threadIdx.x;
    if (i >= N) return;
    float di = rsqrtf(deg_dinv[i] + 1.0f);
    deg_dinv[i] = di;
    float v = x[i] * di;
    A[i * 3 + 0] = v * W1[0];
    A[i * 3 + 1] = v * W1[1];
    A[i * 3 + 2] = v * W1[2];
}

__global__ void scatter_kernel(const int* __restrict__ e, long long E,
                               const int* __restrict__ flag,
                               const float* __restrict__ y, float* __restrict__ acc) {
    const bool i64 = (*flag != 0);
    long long i = (long long)blockIdx.x * blockDim.x + threadIdx.x;
    const long long stride = (long long)gridDim.x * blockDim.x;
    for (; i < E; i += stride) {
        int s, t;
        if (i64) { s = e[2 * i]; t = e[2 * E + 2 * i]; }
        else     { s = e[i];     t = e[E + i]; }
        atomicAdd(acc + (long long)t * 3 + 0, y[(long long)s * 3 + 0]);
        atomicAdd(acc + (long long)t * 3 + 1, y[(long long)s * 3 + 1]);
        atomicAdd(acc + (long long)t * 3 + 2, y[(long long)s * 3 + 2]);
    }
}

__global__ void finalize_mid_kernel(const float* __restrict__ dinv, const float* __restrict__ y,
                                    float* __restrict__ acc, const float* __restrict__ b,
                                    const float* __restrict__ Wn, int N) {
    int i = blockIdx.x * blockDim.x + threadIdx.x;
    if (i >= N) return;
    float di = dinv[i];
    float h0 = fmaxf(di * (acc[i * 3 + 0] + y[i * 3 + 0]) + b[0], 0.0f);
    float h1 = fmaxf(di * (acc[i * 3 + 1] + y[i * 3 + 1]) + b[1], 0.0f);
    float h2 = fmaxf(di * (acc[i * 3 + 2] + y[i * 3 + 2]) + b[2], 0.0f);
    float z0 = di * (h0 * Wn[0] + h1 * Wn[3] + h2 * Wn[6]);
    float z1 = di * (h0 * Wn[1] + h1 * Wn[4] + h2 * Wn[7]);
    float z2 = di * (h0 * Wn[2] + h1 * Wn[5] + h2 * Wn[8]);
    acc[i * 3 + 0] = z0;
    acc[i * 3 + 1] = z1;
    acc[i * 3 + 2] = z2;
}

__global__ void finalize_last_kernel(const float* __restrict__ dinv, const float* __restrict__ y,
                                     const float* __restrict__ acc, const float* __restrict__ b,
                                     float* __restrict__ out, int N) {
    int i = blockIdx.x * blockDim.x + threadIdx.x;
    if (i >= N) return;
    float di = dinv[i];
    out[i * 3 + 0] = fmaxf(di * (acc[i * 3 + 0] + y[i * 3 + 0]) + b[0], 0.0f);
    out[i * 3 + 1] = fmaxf(di * (acc[i * 3 + 1] + y[i * 3 + 1]) + b[1], 0.0f);
    out[i * 3 + 2] = fmaxf(di * (acc[i * 3 + 2] + y[i * 3 + 2]) + b[2], 0.0f);
}

// ---------------- launch ----------------

extern "C" void kernel_launch(void* const* d_in, const int* in_sizes, int n_in,
                              void* d_out, int out_size, void* d_ws, size_t ws_size,
                              hipStream_t stream) {
    const float* x  = (const float*)d_in[0];
    const int*   ei = (const int*)d_in[1];
    const float* W1 = (const float*)d_in[2];
    const float* b1 = (const float*)d_in[3];
    const float* W2 = (const float*)d_in[4];
    const float* b2 = (const float*)d_in[5];
    const float* W3 = (const float*)d_in[6];
    const float* b3 = (const float*)d_in[7];
    float* out = (float*)d_out;

    const long long N = in_sizes[0];
    const long long E = (long long)in_sizes[1] / 2;

    const int nbuck  = (int)((N + BUCKET_SIZE - 1) >> BUCKET_BITS);
    const int ntiles = (int)((E + TILE - 1) / TILE);

    char* w = (char*)d_ws;
    size_t off = 0;
    auto alloc = [&](size_t bytes) -> char* {
        char* pp = w + off;
        off = (off + bytes + 255) & ~(size_t)255;
        return pp;
    };

    int*    flag   = (int*)alloc(4);
    int*    ofs    = (int*)alloc((size_t)ntiles * nbuck * 4);
    int*    ofsT   = (int*)alloc((size_t)nbuck * ntiles * 4);
    int*    bcnt   = (int*)alloc((size_t)nbuck * 4);
    int*    bs     = (int*)alloc(((size_t)nbuck + 1) * 4);
    int*    sofs   = (int*)alloc((size_t)nbuck * 9 * 4);
    int*    packed = (int*)alloc((size_t)ntiles * TILE * 4);
    int*    merged = (int*)alloc((size_t)E * 4);
    float*  dinv   = (float*)alloc((size_t)N * 4);
    float*  p      = (float*)alloc((size_t)N * 4);
    // y2/y3 alias packed (dead after merge); consumers read merged.
    float4* y2     = (float4*)packed;
    float4* y3     = (float4*)((char*)packed + (size_t)N * 16);

    const int nblk = (int)((N + THREADS - 1) / THREADS);

    if (off <= ws_size && N <= (1 << 20) && nbuck <= 1024 && ntiles <= NT_MAX &&
        (size_t)ntiles * TILE * 4 >= (size_t)N * 32) {
        detect_i64_kernel<<<1, 64, 0, stream>>>(ei, flag);
        binsort_kernel<<<ntiles, TPB_S, 0, stream>>>(ei, E, flag, nbuck, packed, ofs);
        dim3 tb(32, 8);
        dim3 tg((nbuck + TRT - 1) / TRT, (ntiles + TRT - 1) / TRT);
        transpose_kernel<<<tg, tb, 0, stream>>>(ofs, ntiles, nbuck, ofsT);
        bcnt_kernel<<<nbuck, THREADS, 0, stream>>>(ofsT, E, ntiles, nbuck, bcnt);
        bscan_kernel<<<1, 1024, 0, stream>>>(bcnt, nbuck, bs);
        merge_kernel<<<nbuck, TPB_S, 0, stream>>>(ofsT, packed, bs, E, ntiles, nbuck,
                                                  x, merged, dinv, p, (int)N);
        slice_reorder_kernel<<<nbuck, THREADS, 0, stream>>>(bs, merged, sofs);

        layer1_bucket_kernel<<<nbuck, THREADS, 0, stream>>>(bs, merged, p, dinv, W1, b1, W2, y2, (int)N);

        // cooperative slice-phased mid/last; graceful fallback to champion kernels
        int Ni = (int)N;
        const int* bs_p = bs; const int* sofs_p = sofs; const int* mg_p = merged;
        const float* dinv_p = dinv;
        const float4* y2_p = y2; float4* y3_p = y3;
        const float* b2_p = b2; const float* W3_p = W3;
        void* argsM[] = {(void*)&bs_p, (void*)&sofs_p, (void*)&mg_p, (void*)&y2_p,
                         (void*)&dinv_p, (void*)&b2_p, (void*)&W3_p, (void*)&y3_p, (void*)&Ni};
        hipError_t ec = hipLaunchCooperativeKernel((void*)layer_mid_coop_kernel,
                                                   dim3(nbuck), dim3(THREADS), argsM, 0, stream);
        if (ec != hipSuccess) {
            layer_mid_bucket_kernel<<<nbuck, THREADS, 0, stream>>>(bs, merged, y2, dinv, b2, W3, y3, (int)N);
        }

        const float4* y3c_p = y3; const float* b3_p = b3; float* out_p = out;
        void* argsL[] = {(void*)&bs_p, (void*)&sofs_p, (void*)&mg_p, (void*)&y3c_p,
                         (void*)&dinv_p, (void*)&b3_p, (void*)&out_p, (void*)&Ni};
        hipError_t ec2 = hipLaunchCooperativeKernel((void*)layer_last_coop_kernel,
                                                    dim3(nbuck), dim3(THREADS), argsL, 0, stream);
        if (ec2 != hipSuccess) {
            layer_last_bucket_kernel<<<nbuck, THREADS, 0, stream>>>(bs, merged, y3, dinv, b3, out, (int)N);
        }
    } else {
        // ---- fallback: atomic scatter path (proven R0) ----
        int*   fflag = (int*)w;
        float* fdinv = (float*)(w + 256);
        float* A     = fdinv + N;
        size_t need_full = 256 + (size_t)N * 4 + (size_t)N * 12 * 2;
        float* B = (ws_size >= need_full) ? (A + 3 * N) : out;
        const int eblk = 2048;

        detect_i64_kernel<<<1, 64, 0, stream>>>(ei, fflag);
        hipMemsetAsync(fdinv, 0, (size_t)N * 4, stream);
        deg_kernel<<<eblk, THREADS, 0, stream>>>(ei, E, fflag, fdinv);
        node_init_kernel<<<nblk, THREADS, 0, stream>>>(x, W1, fdinv, A, (int)N);

        hipMemsetAsync(B, 0, (size_t)N * 12, stream);
        scatter_kernel<<<eblk, THREADS, 0, stream>>>(ei, E, fflag, A, B);
        finalize_mid_kernel<<<nblk, THREADS, 0, stream>>>(fdinv, A, B, b1, W2, (int)N);

        hipMemsetAsync(A, 0, (size_t)N * 12, stream);
        scatter_kernel<<<eblk, THREADS, 0, stream>>>(ei, E, fflag, B, A);
        finalize_mid_kernel<<<nblk, THREADS, 0, stream>>>(fdinv, B, A, b2, W3, (int)N);

        hipMemsetAsync(B, 0, (size_t)N * 12, stream);
        scatter_kernel<<<eblk, THREADS, 0, stream>>>(ei, E, fflag, A, B);
        finalize_last_kernel<<<nblk, THREADS, 0, stream>>>(fdinv, A, B, b3, out, (int)N);
    }
}

// Round 13
// 762.846 us; speedup vs baseline: 3.4738x; 3.4738x over previous
//
#include <hip/hip_runtime.h>

#define THREADS 256
#define TILE 8192
#define TPB_S 512
#define EPT 16              // TILE / TPB_S
#define BUCKET_BITS 10
#define BUCKET_SIZE 1024
#define NT_MAX 2048         // max tiles supported by merge (E <= 16.7M)
#define STAGE_CAP 15616     // 61KB stage; merge LDS total 75KB -> 2 blocks/CU
#define MSK 0xFFFFFu

__device__ __forceinline__ long long llmin(long long a, long long b) { return a < b ? a : b; }

// ---------------- common ----------------

__global__ void detect_i64_kernel(const int* __restrict__ e, int* __restrict__ flag) {
    if (blockIdx.x == 0 && threadIdx.x == 0) {
        bool all_odd_zero = true, any_even = false;
#pragma unroll
        for (int k = 0; k < 16; ++k) {
            if (e[2 * k + 1] != 0) all_odd_zero = false;
            if (e[2 * k] != 0) any_even = true;
        }
        *flag = (all_odd_zero && any_even) ? 1 : 0;
    }
}

// ---------------- single-pass tile-local counting sort (champion R6) ----------------

__global__ __launch_bounds__(TPB_S) void binsort_kernel(
        const int* __restrict__ e, long long E, const int* __restrict__ flag,
        int nbuck, int* __restrict__ packed, int* __restrict__ ofs) {
    __shared__ int hist[1024];
    __shared__ int sarr[TPB_S];
    __shared__ int srec[TILE];
    const int tid = threadIdx.x;
    hist[tid] = 0;
    hist[tid + TPB_S] = 0;
    __syncthreads();

    const bool i64 = (*flag != 0);
    const long long beg = (long long)blockIdx.x * TILE;
    const int tile_len = (int)llmin((long long)TILE, E - beg);

    int rec[EPT];
    int bkt[EPT];
#pragma unroll
    for (int k = 0; k < EPT; ++k) {
        int j = tid + k * TPB_S;
        bkt[k] = -1;
        if (j < tile_len) {
            long long idx = beg + j;
            int s, d;
            if (i64) { s = ((const int2*)e)[idx].x; d = ((const int2*)e)[E + idx].x; }
            else     { s = e[idx];                  d = e[E + idx]; }
            bkt[k] = d >> BUCKET_BITS;
            rec[k] = ((d & (BUCKET_SIZE - 1)) << 20) | s;
            atomicAdd(&hist[bkt[k]], 1);
        }
    }
    __syncthreads();

    int v0 = hist[2 * tid], v1 = hist[2 * tid + 1];
    sarr[tid] = v0 + v1;
    __syncthreads();
    for (int off = 1; off < TPB_S; off <<= 1) {
        int t = (tid >= off) ? sarr[tid - off] : 0;
        __syncthreads();
        sarr[tid] += t;
        __syncthreads();
    }
    int excl = (tid == 0) ? 0 : sarr[tid - 1];
    hist[2 * tid] = excl;
    hist[2 * tid + 1] = excl + v0;
    __syncthreads();

    int* orow = ofs + (size_t)blockIdx.x * nbuck;
    if (tid < nbuck) orow[tid] = hist[tid];
    if (tid + TPB_S < nbuck) orow[tid + TPB_S] = hist[tid + TPB_S];
    __syncthreads();

#pragma unroll
    for (int k = 0; k < EPT; ++k) {
        if (bkt[k] >= 0) {
            int pos = atomicAdd(&hist[bkt[k]], 1);
            srec[pos] = rec[k];
        }
    }
    __syncthreads();

    int* prow = packed + (size_t)blockIdx.x * TILE;
    for (int j = tid; j < tile_len; j += TPB_S) prow[j] = srec[j];
}

// transpose ofs[t][b] -> ofsT[b][t]
#define TRT 32
__global__ void transpose_kernel(const int* __restrict__ in, int rows, int cols,
                                 int* __restrict__ outT) {
    __shared__ int tb[TRT][TRT + 1];
    int c0 = blockIdx.x * TRT, r0 = blockIdx.y * TRT;
    int lx = threadIdx.x, ly = threadIdx.y;   // 32 x 8
    for (int dy = ly; dy < TRT; dy += 8) {
        int r = r0 + dy, c = c0 + lx;
        if (r < rows && c < cols) tb[dy][lx] = in[(size_t)r * cols + c];
    }
    __syncthreads();
    for (int dy = ly; dy < TRT; dy += 8) {
        int r = c0 + dy, c = r0 + lx;
        if (r < cols && c < rows) outT[(size_t)r * rows + c] = tb[lx][dy];
    }
}

// ---------------- bucket sizes + global offsets (no atomics) ----------------

__global__ __launch_bounds__(THREADS) void bcnt_kernel(
        const int* __restrict__ ofsT, long long E, int ntiles, int nbuck,
        int* __restrict__ bcnt) {
    __shared__ int sh[THREADS];
    const int b = blockIdx.x, tid = threadIdx.x;
    const int* row0 = ofsT + (size_t)b * ntiles;
    const int* row1 = row0 + ntiles;
    const bool last_b = (b == nbuck - 1);
    int s = 0;
    for (int t = tid; t < ntiles; t += THREADS) {
        int o = row0[t];
        int tl = (t == ntiles - 1) ? (int)(E - (long long)t * TILE) : TILE;
        int o2 = last_b ? tl : row1[t];
        s += o2 - o;
    }
    sh[tid] = s;
    __syncthreads();
    for (int off = THREADS >> 1; off > 0; off >>= 1) {
        if (tid < off) sh[tid] += sh[tid + off];
        __syncthreads();
    }
    if (tid == 0) bcnt[b] = sh[0];
}

__global__ __launch_bounds__(1024) void bscan_kernel(
        const int* __restrict__ bcnt, int nbuck, int* __restrict__ bs) {
    __shared__ int sh[1024];
    int tid = threadIdx.x;
    int v = (tid < nbuck) ? bcnt[tid] : 0;
    sh[tid] = v;
    __syncthreads();
    for (int off = 1; off < 1024; off <<= 1) {
        int t = (tid >= off) ? sh[tid - off] : 0;
        __syncthreads();
        sh[tid] += t;
        __syncthreads();
    }
    if (tid < nbuck) bs[tid] = sh[tid] - v;
    if (tid == nbuck - 1) bs[nbuck] = sh[tid];
}

// ---------------- merge: tile-runs -> bucket-contiguous + fused deg/dinv/p ----------------

__global__ __launch_bounds__(TPB_S) void merge_kernel(
        const int* __restrict__ ofsT, const int* __restrict__ packed,
        const int* __restrict__ bs, long long E, int ntiles, int nbuck,
        const float* __restrict__ x,
        int* __restrict__ merged, float* __restrict__ dinv, float* __restrict__ p,
        int N) {
    __shared__ int lofs[NT_MAX];
    __shared__ int tsum[TPB_S];
    __shared__ int stage[STAGE_CAP];
    __shared__ int cnt[BUCKET_SIZE];
    const int tid = threadIdx.x, b = blockIdx.x;
    const int* row0 = ofsT + (size_t)b * ntiles;
    const int* row1 = row0 + ntiles;
    const bool last_b = (b == nbuck - 1);
    const int per = (ntiles + TPB_S - 1) / TPB_S;
    const int t0 = tid * per;

    for (int k = tid; k < BUCKET_SIZE; k += TPB_S) cnt[k] = 0;

    int s = 0;
    for (int k = 0; k < per; ++k) {
        int t = t0 + k;
        if (t < ntiles) {
            int o = row0[t];
            int tl = (t == ntiles - 1) ? (int)(E - (long long)t * TILE) : TILE;
            int o2 = last_b ? tl : row1[t];
            lofs[t] = s;
            s += o2 - o;
        }
    }
    tsum[tid] = s;
    __syncthreads();
    for (int off = 1; off < TPB_S; off <<= 1) {
        int t = (tid >= off) ? tsum[tid - off] : 0;
        __syncthreads();
        tsum[tid] += t;
        __syncthreads();
    }
    const int excl = tsum[tid] - s;
    const int total = tsum[TPB_S - 1];
    for (int k = 0; k < per; ++k) {
        int t = t0 + k;
        if (t < ntiles) lofs[t] += excl;
    }
    __syncthreads();

    const int bsb = bs[b];
    for (int k = 0; k < per; ++k) {
        int t = t0 + k;
        if (t >= ntiles) break;
        int o = row0[t];
        int tl = (t == ntiles - 1) ? (int)(E - (long long)t * TILE) : TILE;
        int o2 = last_b ? tl : row1[t];
        const int* pr = packed + (size_t)t * TILE;
        int q = lofs[t];
        int j = o;
        for (; j + 4 <= o2; j += 4, q += 4) {
            int a0 = pr[j], a1 = pr[j + 1], a2 = pr[j + 2], a3 = pr[j + 3];
            atomicAdd(&cnt[((unsigned)a0) >> 20], 1);
            atomicAdd(&cnt[((unsigned)a1) >> 20], 1);
            atomicAdd(&cnt[((unsigned)a2) >> 20], 1);
            atomicAdd(&cnt[((unsigned)a3) >> 20], 1);
            if (q + 3 < STAGE_CAP) {
                stage[q] = a0; stage[q + 1] = a1; stage[q + 2] = a2; stage[q + 3] = a3;
            } else {
                if (q < STAGE_CAP) stage[q] = a0; else merged[bsb + q] = a0;
                if (q + 1 < STAGE_CAP) stage[q + 1] = a1; else merged[bsb + q + 1] = a1;
                if (q + 2 < STAGE_CAP) stage[q + 2] = a2; else merged[bsb + q + 2] = a2;
                merged[bsb + q + 3] = a3;
            }
        }
        for (; j < o2; ++j, ++q) {
            int a0 = pr[j];
            atomicAdd(&cnt[((unsigned)a0) >> 20], 1);
            if (q < STAGE_CAP) stage[q] = a0; else merged[bsb + q] = a0;
        }
    }
    __syncthreads();

    const int wlen = total < STAGE_CAP ? total : STAGE_CAP;
    for (int j = tid; j < wlen; j += TPB_S) merged[bsb + j] = stage[j];

    int nbase = b << BUCKET_BITS;
    for (int j = tid; j < BUCKET_SIZE; j += TPB_S) {
        int i = nbase + j;
        if (i < N) {
            float di = rsqrtf((float)cnt[j] + 1.0f);
            dinv[i] = di;
            p[i] = x[i] * di;
        }
    }
}

// ---------------- bucketed fused layers (champion R6: 256 threads, 4-way) ----------------

__global__ void layer1_bucket_kernel(const int* __restrict__ bs, const int* __restrict__ packed,
                                     const float* __restrict__ p, const float* __restrict__ dinv,
                                     const float* __restrict__ W1, const float* __restrict__ b1,
                                     const float* __restrict__ W2,
                                     float4* __restrict__ y2, int N) {
    __shared__ float acc[BUCKET_SIZE];
    for (int k = threadIdx.x; k < BUCKET_SIZE; k += blockDim.x) acc[k] = 0.0f;
    __syncthreads();
    int beg = bs[blockIdx.x], end = bs[blockIdx.x + 1];
    int stride = blockDim.x;
    int k = beg + threadIdx.x;
    for (; k + 3 * stride < end; k += 4 * stride) {
        unsigned r0 = packed[k], r1 = packed[k + stride];
        unsigned r2 = packed[k + 2 * stride], r3 = packed[k + 3 * stride];
        float v0 = p[r0 & MSK], v1 = p[r1 & MSK];
        float v2 = p[r2 & MSK], v3 = p[r3 & MSK];
        atomicAdd(&acc[r0 >> 20], v0);
        atomicAdd(&acc[r1 >> 20], v1);
        atomicAdd(&acc[r2 >> 20], v2);
        atomicAdd(&acc[r3 >> 20], v3);
    }
    for (; k < end; k += stride) {
        unsigned rec = (unsigned)packed[k];
        atomicAdd(&acc[rec >> 20], p[rec & MSK]);
    }
    __syncthreads();
    int base = blockIdx.x << BUCKET_BITS;
    for (int j = threadIdx.x; j < BUCKET_SIZE; j += blockDim.x) {
        int i = base + j;
        if (i >= N) continue;
        float di = dinv[i];
        float t = di * (acc[j] + p[i]);
        float h0 = fmaxf(t * W1[0] + b1[0], 0.0f);
        float h1 = fmaxf(t * W1[1] + b1[1], 0.0f);
        float h2 = fmaxf(t * W1[2] + b1[2], 0.0f);
        float4 o;
        o.x = di * (h0 * W2[0] + h1 * W2[3] + h2 * W2[6]);
        o.y = di * (h0 * W2[1] + h1 * W2[4] + h2 * W2[7]);
        o.z = di * (h0 * W2[2] + h1 * W2[5] + h2 * W2[8]);
        o.w = 0.0f;
        y2[i] = o;
    }
}

__global__ void layer_mid_bucket_kernel(const int* __restrict__ bs, const int* __restrict__ packed,
                                        const float4* __restrict__ y, const float* __restrict__ dinv,
                                        const float* __restrict__ b, const float* __restrict__ Wn,
                                        float4* __restrict__ ynext, int N) {
    __shared__ float acc[BUCKET_SIZE * 3];
    for (int k = threadIdx.x; k < BUCKET_SIZE * 3; k += blockDim.x) acc[k] = 0.0f;
    __syncthreads();
    int beg = bs[blockIdx.x], end = bs[blockIdx.x + 1];
    int stride = blockDim.x;
    int k = beg + threadIdx.x;
    for (; k + 3 * stride < end; k += 4 * stride) {
        unsigned r0 = packed[k], r1 = packed[k + stride];
        unsigned r2 = packed[k + 2 * stride], r3 = packed[k + 3 * stride];
        float4 v0 = y[r0 & MSK], v1 = y[r1 & MSK];
        float4 v2 = y[r2 & MSK], v3 = y[r3 & MSK];
        int d0 = (r0 >> 20) * 3, d1 = (r1 >> 20) * 3, d2 = (r2 >> 20) * 3, d3 = (r3 >> 20) * 3;
        atomicAdd(&acc[d0 + 0], v0.x); atomicAdd(&acc[d0 + 1], v0.y); atomicAdd(&acc[d0 + 2], v0.z);
        atomicAdd(&acc[d1 + 0], v1.x); atomicAdd(&acc[d1 + 1], v1.y); atomicAdd(&acc[d1 + 2], v1.z);
        atomicAdd(&acc[d2 + 0], v2.x); atomicAdd(&acc[d2 + 1], v2.y); atomicAdd(&acc[d2 + 2], v2.z);
        atomicAdd(&acc[d3 + 0], v3.x); atomicAdd(&acc[d3 + 1], v3.y); atomicAdd(&acc[d3 + 2], v3.z);
    }
    for (; k < end; k += stride) {
        unsigned rec = (unsigned)packed[k];
        float4 v = y[rec & MSK];
        int dl = (rec >> 20) * 3;
        atomicAdd(&acc[dl + 0], v.x);
        atomicAdd(&acc[dl + 1], v.y);
        atomicAdd(&acc[dl + 2], v.z);
    }
    __syncthreads();
    int base = blockIdx.x << BUCKET_BITS;
    for (int j = threadIdx.x; j < BUCKET_SIZE; j += blockDim.x) {
        int i = base + j;
        if (i >= N) continue;
        float di = dinv[i];
        float4 yi = y[i];
        float h0 = fmaxf(di * (acc[j * 3 + 0] + yi.x) + b[0], 0.0f);
        float h1 = fmaxf(di * (acc[j * 3 + 1] + yi.y) + b[1], 0.0f);
        float h2 = fmaxf(di * (acc[j * 3 + 2] + yi.z) + b[2], 0.0f);
        float4 o;
        o.x = di * (h0 * Wn[0] + h1 * Wn[3] + h2 * Wn[6]);
        o.y = di * (h0 * Wn[1] + h1 * Wn[4] + h2 * Wn[7]);
        o.z = di * (h0 * Wn[2] + h1 * Wn[5] + h2 * Wn[8]);
        o.w = 0.0f;
        ynext[i] = o;
    }
}

__global__ void layer_last_bucket_kernel(const int* __restrict__ bs, const int* __restrict__ packed,
                                         const float4* __restrict__ y, const float* __restrict__ dinv,
                                         const float* __restrict__ b,
                                         float* __restrict__ out, int N) {
    __shared__ float acc[BUCKET_SIZE * 3];
    for (int k = threadIdx.x; k < BUCKET_SIZE * 3; k += blockDim.x) acc[k] = 0.0f;
    __syncthreads();
    int beg = bs[blockIdx.x], end = bs[blockIdx.x + 1];
    int stride = blockDim.x;
    int k = beg + threadIdx.x;
    for (; k + 3 * stride < end; k += 4 * stride) {
        unsigned r0 = packed[k], r1 = packed[k + stride];
        unsigned r2 = packed[k + 2 * stride], r3 = packed[k + 3 * stride];
        float4 v0 = y[r0 & MSK], v1 = y[r1 & MSK];
        float4 v2 = y[r2 & MSK], v3 = y[r3 & MSK];
        int d0 = (r0 >> 20) * 3, d1 = (r1 >> 20) * 3, d2 = (r2 >> 20) * 3, d3 = (r3 >> 20) * 3;
        atomicAdd(&acc[d0 + 0], v0.x); atomicAdd(&acc[d0 + 1], v0.y); atomicAdd(&acc[d0 + 2], v0.z);
        atomicAdd(&acc[d1 + 0], v1.x); atomicAdd(&acc[d1 + 1], v1.y); atomicAdd(&acc[d1 + 2], v1.z);
        atomicAdd(&acc[d2 + 0], v2.x); atomicAdd(&acc[d2 + 1], v2.y); atomicAdd(&acc[d2 + 2], v2.z);
        atomicAdd(&acc[d3 + 0], v3.x); atomicAdd(&acc[d3 + 1], v3.y); atomicAdd(&acc[d3 + 2], v3.z);
    }
    for (; k < end; k += stride) {
        unsigned rec = (unsigned)packed[k];
        float4 v = y[rec & MSK];
        int dl = (rec >> 20) * 3;
        atomicAdd(&acc[dl + 0], v.x);
        atomicAdd(&acc[dl + 1], v.y);
        atomicAdd(&acc[dl + 2], v.z);
    }
    __syncthreads();
    int base = blockIdx.x << BUCKET_BITS;
    for (int j = threadIdx.x; j < BUCKET_SIZE; j += blockDim.x) {
        int i = base + j;
        if (i >= N) continue;
        float di = dinv[i];
        float4 yi = y[i];
        out[i * 3 + 0] = fmaxf(di * (acc[j * 3 + 0] + yi.x) + b[0], 0.0f);
        out[i * 3 + 1] = fmaxf(di * (acc[j * 3 + 1] + yi.y) + b[1], 0.0f);
        out[i * 3 + 2] = fmaxf(di * (acc[j * 3 + 2] + yi.z) + b[2], 0.0f);
    }
}

// ---------------- fallback (atomic scatter path, known-good R0) ----------------

__global__ void deg_kernel(const int* __restrict__ e, long long E,
                           const int* __restrict__ flag, float* __restrict__ deg) {
    const bool i64 = (*flag != 0);
    long long i = (long long)blockIdx.x * blockDim.x + threadIdx.x;
    const long long stride = (long long)gridDim.x * blockDim.x;
    for (; i < E; i += stride) {
        long long t = i64 ? (long long)e[2 * E + 2 * i] : (long long)e[E + i];
        atomicAdd(deg + t, 1.0f);
    }
}

__global__ void node_init_kernel(const float* __restrict__ x, const float* __restrict__ W1,
                                 float* __restrict__ deg_dinv, float* __restrict__ A, int N) {
    int i = blockIdx.x * blockDim.x + threadIdx.x;
    if (i >= N) return;
    float di = rsqrtf(deg_dinv[i] + 1.0f);
    deg_dinv[i] = di;
    float v = x[i] * di;
    A[i * 3 + 0] = v * W1[0];
    A[i * 3 + 1] = v * W1[1];
    A[i * 3 + 2] = v * W1[2];
}

__global__ void scatter_kernel(const int* __restrict__ e, long long E,
                               const int* __restrict__ flag,
                               const float* __restrict__ y, float* __restrict__ acc) {
    const bool i64 = (*flag != 0);
    long long i = (long long)blockIdx.x * blockDim.x + threadIdx.x;
    const long long stride = (long long)gridDim.x * blockDim.x;
    for (; i < E; i += stride) {
        int s, t;
        if (i64) { s = e[2 * i]; t = e[2 * E + 2 * i]; }
        else     { s = e[i];     t = e[E + i]; }
        atomicAdd(acc + (long long)t * 3 + 0, y[(long long)s * 3 + 0]);
        atomicAdd(acc + (long long)t * 3 + 1, y[(long long)s * 3 + 1]);
        atomicAdd(acc + (long long)t * 3 + 2, y[(long long)s * 3 + 2]);
    }
}

__global__ void finalize_mid_kernel(const float* __restrict__ dinv, const float* __restrict__ y,
                                    float* __restrict__ acc, const float* __restrict__ b,
                                    const float* __restrict__ Wn, int N) {
    int i = blockIdx.x * blockDim.x + threadIdx.x;
    if (i >= N) return;
    float di = dinv[i];
    float h0 = fmaxf(di * (acc[i * 3 + 0] + y[i * 3 + 0]) + b[0], 0.0f);
    float h1 = fmaxf(di * (acc[i * 3 + 1] + y[i * 3 + 1]) + b[1], 0.0f);
    float h2 = fmaxf(di * (acc[i * 3 + 2] + y[i * 3 + 2]) + b[2], 0.0f);
    float z0 = di * (h0 * Wn[0] + h1 * Wn[3] + h2 * Wn[6]);
    float z1 = di * (h0 * Wn[1] + h1 * Wn[4] + h2 * Wn[7]);
    float z2 = di * (h0 * Wn[2] + h1 * Wn[5] + h2 * Wn[8]);
    acc[i * 3 + 0] = z0;
    acc[i * 3 + 1] = z1;
    acc[i * 3 + 2] = z2;
}

__global__ void finalize_last_kernel(const float* __restrict__ dinv, const float* __restrict__ y,
                                     const float* __restrict__ acc, const float* __restrict__ b,
                                     float* __restrict__ out, int N) {
    int i = blockIdx.x * blockDim.x + threadIdx.x;
    if (i >= N) return;
    float di = dinv[i];
    out[i * 3 + 0] = fmaxf(di * (acc[i * 3 + 0] + y[i * 3 + 0]) + b[0], 0.0f);
    out[i * 3 + 1] = fmaxf(di * (acc[i * 3 + 1] + y[i * 3 + 1]) + b[1], 0.0f);
    out[i * 3 + 2] = fmaxf(di * (acc[i * 3 + 2] + y[i * 3 + 2]) + b[2], 0.0f);
}

// ---------------- launch ----------------

extern "C" void kernel_launch(void* const* d_in, const int* in_sizes, int n_in,
                              void* d_out, int out_size, void* d_ws, size_t ws_size,
                              hipStream_t stream) {
    const float* x  = (const float*)d_in[0];
    const int*   ei = (const int*)d_in[1];
    const float* W1 = (const float*)d_in[2];
    const float* b1 = (const float*)d_in[3];
    const float* W2 = (const float*)d_in[4];
    const float* b2 = (const float*)d_in[5];
    const float* W3 = (const float*)d_in[6];
    const float* b3 = (const float*)d_in[7];
    float* out = (float*)d_out;

    const long long N = in_sizes[0];
    const long long E = (long long)in_sizes[1] / 2;

    const int nbuck  = (int)((N + BUCKET_SIZE - 1) >> BUCKET_BITS);
    const int ntiles = (int)((E + TILE - 1) / TILE);

    char* w = (char*)d_ws;
    size_t off = 0;
    auto alloc = [&](size_t bytes) -> char* {
        char* pp = w + off;
        off = (off + bytes + 255) & ~(size_t)255;
        return pp;
    };

    int*    flag   = (int*)alloc(4);
    int*    ofs    = (int*)alloc((size_t)ntiles * nbuck * 4);
    int*    ofsT   = (int*)alloc((size_t)nbuck * ntiles * 4);
    int*    bcnt   = (int*)alloc((size_t)nbuck * 4);
    int*    bs     = (int*)alloc(((size_t)nbuck + 1) * 4);
    int*    packed = (int*)alloc((size_t)ntiles * TILE * 4);
    int*    merged = (int*)alloc((size_t)E * 4);
    float*  dinv   = (float*)alloc((size_t)N * 4);
    float*  p      = (float*)alloc((size_t)N * 4);
    // y2/y3 alias packed: packed is dead after merge; consumers read merged.
    float4* y2     = (float4*)packed;
    float4* y3     = (float4*)((char*)packed + (size_t)N * 16);

    const int nblk = (int)((N + THREADS - 1) / THREADS);

    if (off <= ws_size && N <= (1 << 20) && nbuck <= 1024 && ntiles <= NT_MAX &&
        (size_t)ntiles * TILE * 4 >= (size_t)N * 32) {
        detect_i64_kernel<<<1, 64, 0, stream>>>(ei, flag);
        binsort_kernel<<<ntiles, TPB_S, 0, stream>>>(ei, E, flag, nbuck, packed, ofs);
        dim3 tb(32, 8);
        dim3 tg((nbuck + TRT - 1) / TRT, (ntiles + TRT - 1) / TRT);
        transpose_kernel<<<tg, tb, 0, stream>>>(ofs, ntiles, nbuck, ofsT);
        bcnt_kernel<<<nbuck, THREADS, 0, stream>>>(ofsT, E, ntiles, nbuck, bcnt);
        bscan_kernel<<<1, 1024, 0, stream>>>(bcnt, nbuck, bs);
        merge_kernel<<<nbuck, TPB_S, 0, stream>>>(ofsT, packed, bs, E, ntiles, nbuck,
                                                  x, merged, dinv, p, (int)N);

        layer1_bucket_kernel<<<nbuck, THREADS, 0, stream>>>(bs, merged, p, dinv, W1, b1, W2, y2, (int)N);
        layer_mid_bucket_kernel<<<nbuck, THREADS, 0, stream>>>(bs, merged, y2, dinv, b2, W3, y3, (int)N);
        layer_last_bucket_kernel<<<nbuck, THREADS, 0, stream>>>(bs, merged, y3, dinv, b3, out, (int)N);
    } else {
        // ---- fallback: atomic scatter path (proven R0) ----
        int*   fflag = (int*)w;
        float* fdinv = (float*)(w + 256);
        float* A     = fdinv + N;
        size_t need_full = 256 + (size_t)N * 4 + (size_t)N * 12 * 2;
        float* B = (ws_size >= need_full) ? (A + 3 * N) : out;
        const int eblk = 2048;

        detect_i64_kernel<<<1, 64, 0, stream>>>(ei, fflag);
        hipMemsetAsync(fdinv, 0, (size_t)N * 4, stream);
        deg_kernel<<<eblk, THREADS, 0, stream>>>(ei, E, fflag, fdinv);
        node_init_kernel<<<nblk, THREADS, 0, stream>>>(x, W1, fdinv, A, (int)N);

        hipMemsetAsync(B, 0, (size_t)N * 12, stream);
        scatter_kernel<<<eblk, THREADS, 0, stream>>>(ei, E, fflag, A, B);
        finalize_mid_kernel<<<nblk, THREADS, 0, stream>>>(fdinv, A, B, b1, W2, (int)N);

        hipMemsetAsync(A, 0, (size_t)N * 12, stream);
        scatter_kernel<<<eblk, THREADS, 0, stream>>>(ei, E, fflag, B, A);
        finalize_mid_kernel<<<nblk, THREADS, 0, stream>>>(fdinv, B, A, b2, W3, (int)N);

        hipMemsetAsync(B, 0, (size_t)N * 12, stream);
        scatter_kernel<<<eblk, THREADS, 0, stream>>>(ei, E, fflag, A, B);
        finalize_last_kernel<<<nblk, THREADS, 0, stream>>>(fdinv, A, B, b3, out, (int)N);
    }
}